// Round 7
// baseline (82.466 us; speedup 1.0000x reference)
//
#include <hip/hip_runtime.h>
#include <stdint.h>

// LIF spiking scan: x[B=8, S=2048, H=4096] f32 -> spikes[B,S,H] f32.
// R6 post-mortem: 2-wave producer/consumer hit 81us (6.6 TB/s logical).
// Remaining suspect: the single DMA wave still serializes load-wait,
// load-issue, and the flush's ds_read/lgkm chains. R7: 3-WAVE SPLIT.
//   wave 0 compute: s_barrier -> 64-step LIF chain -> lgkmcnt(0).
//   wave 1 loader:  counted vmcnt(16) wait for L(t) (its counter holds ONLY
//                   loads) -> s_barrier -> issue L(t+2) (after barrier, so
//                   compute has finished reading that xbuf slot).
//   wave 2 storer:  s_barrier -> flush F(t-1) (ds_read+nt store) ->
//                   lgkmcnt(0) before next barrier (WAR vs compute's obuf
//                   rewrite). Never waits vmcnt; stores self-drain.
// All waves execute exactly NT+1 s_barriers. 512 blocks x 192 thr ->
// 2 blocks/CU (80KB LDS each = full 160KB pool), 6 waves/CU.
// Bit-exact vs numpy: the carried state is dmem = decay*mem (one rounding),
// memn = dmem + x (second rounding) == __fadd_rn(__fmul_rn(decay,mem),x);
// reset gives dmem = 0 = decay*0 exactly. No FMA contraction anywhere.

#define S_LEN 2048
#define H_DIM 4096
#define TS 64              // timesteps per tile
#define NT (S_LEN / TS)    // 32 tiles

typedef __attribute__((address_space(3))) uint32_t lds_u32;
typedef __attribute__((address_space(1))) const uint32_t gbl_u32;
typedef float f32x4 __attribute__((ext_vector_type(4)));

__global__ __launch_bounds__(192, 1) void lif_kernel(
    const float* __restrict__ x,
    const float* __restrict__ thr_p,
    const float* __restrict__ decay_p,
    float* __restrict__ out)
{
    __shared__ __attribute__((aligned(16))) float xbuf[3][TS][64];  // 48 KB
    __shared__ __attribute__((aligned(16))) float obuf[2][TS][64];  // 32 KB

    const int lane = threadIdx.x & 63;
    const int wid  = threadIdx.x >> 6;       // 0 compute, 1 loader, 2 storer
    const int b    = blockIdx.x >> 6;        // 0..7
    const int h0   = (blockIdx.x & 63) * 64; // h-tile origin
    const size_t seq_base = (size_t)b * S_LEN * H_DIM;

    if (wid == 1) {
        // ---------------- loader wave ----------------
        const int lrow = lane >> 4;              // 0..3
        const int lcol = (lane & 15) * 4;        // 0..60
        const float* gsrc0 = x + seq_base + (size_t)lrow * H_DIM + h0 + lcol;

        asm volatile("s_waitcnt vmcnt(0) lgkmcnt(0)" ::: "memory");

        // 16 width-16 global->LDS loads (1 KB/op); LDS dest wave-uniform
        // base + lane*16 lands as [s_local][h_local].
        auto issue_tile = [&](int t, int buf) {
            const float* g = gsrc0 + (size_t)t * TS * H_DIM;
#pragma unroll
            for (int k = 0; k < 16; ++k) {
                __builtin_amdgcn_global_load_lds(
                    (gbl_u32*)(g + (size_t)k * 4 * H_DIM),
                    (lds_u32*)&xbuf[buf][k * 4][0],
                    16, 0, 0);
            }
        };

        issue_tile(0, 0);
        issue_tile(1, 1);

        for (int t = 0; t < NT; ++t) {
            // Outstanding here: L(t), L(t+1 if exists). Wait for L(t).
            if (t == NT - 1) asm volatile("s_waitcnt vmcnt(0)"  ::: "memory");
            else             asm volatile("s_waitcnt vmcnt(16)" ::: "memory");
            asm volatile("s_barrier" ::: "memory");              // #t
            // Safe only after barrier #t: compute finished reading
            // xbuf[(t-1)%3] == xbuf[(t+2)%3] before arriving there.
            if (t + 2 < NT) issue_tile(t + 2, (t + 2) % 3);
        }
        asm volatile("s_barrier" ::: "memory");                  // #NT
    } else if (wid == 2) {
        // ---------------- storer wave ----------------
        const int lrow = lane >> 4;
        const int lcol = (lane & 15) * 4;
        float* gdst0 = out + seq_base + (size_t)lrow * H_DIM + h0 + lcol;

        // 16x 1KB nontemporal dwordx4 stores from obuf[t&1] -> out tile t.
        auto flush_tile = [&](int t) {
            float*       gd   = gdst0 + (size_t)t * TS * H_DIM;
            const float* lsrc = &obuf[t & 1][0][0];
#pragma unroll
            for (int k = 0; k < 16; ++k) {
                const f32x4 v = *(const f32x4*)(lsrc + k * 256 + lane * 4);
                __builtin_nontemporal_store(v, (f32x4*)(gd + (size_t)k * 4 * H_DIM));
            }
        };

        for (int t = 0; t < NT; ++t) {
            asm volatile("s_barrier" ::: "memory");              // #t
            if (t >= 1) {
                flush_tile(t - 1);
                // ds_reads of obuf[(t-1)&1] must retire before compute
                // rewrites that parity during iter t+1 (post barrier #t+1).
                asm volatile("s_waitcnt lgkmcnt(0)" ::: "memory");
            }
        }
        asm volatile("s_barrier" ::: "memory");                  // #NT
        flush_tile(NT - 1);
    } else {
        // ---------------- compute wave ----------------
        const float thr   = thr_p[0];
        const float decay = decay_p[0];

        float dmem = 0.0f;   // carries decay*mem (exactly one rounding)
        float ref  = 0.0f;

        for (int t = 0; t < NT; ++t) {
            asm volatile("s_barrier" ::: "memory");              // #t
            const float* xb = &xbuf[t % 3][0][0];
            float*       ob = &obuf[t & 1][0][0];
#pragma unroll
            for (int s = 0; s < TS; ++s) {
                const float xv   = xb[s * 64 + lane];
                const float memn = __fadd_rn(dmem, xv);          // decay*mem + x
                const float refm = fmaxf(__fadd_rn(ref, -1.0f), 0.0f);
                const bool  spk  = (refm == 0.0f) & (memn > thr);
                const float dm   = __fmul_rn(decay, memn);       // speculative decay
                dmem = spk ? 0.0f : dm;                          // decay * mem_next, exact
                ref  = __fadd_rn(refm, spk ? 5.0f : 0.0f);       // exact
                ob[s * 64 + lane] = spk ? 1.0f : 0.0f;
            }
            // xbuf reads + obuf writes retired before next barrier.
            asm volatile("s_waitcnt lgkmcnt(0)" ::: "memory");
        }
        asm volatile("s_barrier" ::: "memory");                  // #NT
    }
}

extern "C" void kernel_launch(void* const* d_in, const int* in_sizes, int n_in,
                              void* d_out, int out_size, void* d_ws, size_t ws_size,
                              hipStream_t stream) {
    const float* x     = (const float*)d_in[0];
    const float* thr   = (const float*)d_in[1];
    const float* decay = (const float*)d_in[2];
    float*       out   = (float*)d_out;

    // 512 blocks x 192 threads (compute + loader + storer per h-tile);
    // 2 blocks/CU, 6 waves/CU, 160KB LDS/CU fully used.
    lif_kernel<<<dim3(512), dim3(192), 0, stream>>>(x, thr, decay, out);
}

// Round 8
// 80.640 us; speedup vs baseline: 1.0226x; 1.0226x over previous
//
#include <hip/hip_runtime.h>
#include <stdint.h>

// LIF spiking scan: x[B=8, S=2048, H=4096] f32 -> spikes[B,S,H] f32.
// R7 post-mortem: 3-wave split neutral vs R6 -> DMA serialization is not the
// limiter; HBM side runs 4.9 TB/s vs 6.3 achievable. Hypothesis: 64-wide
// h-tiles give only 256B contiguous per DRAM-row visit (4 rows/op at 16KB
// stride). R8: h-tile width 128 -> every VMEM op covers 2 rows x 512B
// contiguous (2x burst length), same decoupled wave-specialized skeleton.
//   256 blocks (8 b x 32 h-tiles) x 256 thr = 2 compute waves + loader +
//   storer; TS=32, NT=64, xbuf[3]+obuf[2] = 80KB LDS, 1 block/CU.
// Bit-exact vs numpy: carried state dmem = decay*mem (one rounding),
// memn = dmem + x (second) == unfused mul+add; reset -> dmem=0 exact.

#define S_LEN 2048
#define H_DIM 4096
#define HT 128             // h-tile width
#define TS 32              // timesteps per tile
#define NT (S_LEN / TS)    // 64 tiles
#define OPS (TS / 2)       // 16 VMEM ops per tile (2 rows per 1KB op)

typedef __attribute__((address_space(3))) uint32_t lds_u32;
typedef __attribute__((address_space(1))) const uint32_t gbl_u32;
typedef float f32x4 __attribute__((ext_vector_type(4)));

__global__ __launch_bounds__(256, 1) void lif_kernel(
    const float* __restrict__ x,
    const float* __restrict__ thr_p,
    const float* __restrict__ decay_p,
    float* __restrict__ out)
{
    __shared__ __attribute__((aligned(16))) float xbuf[3][TS][HT];  // 48 KB
    __shared__ __attribute__((aligned(16))) float obuf[2][TS][HT];  // 32 KB

    const int lane = threadIdx.x & 63;
    const int wid  = threadIdx.x >> 6;       // 0,1 compute; 2 loader; 3 storer
    const int b    = blockIdx.x >> 5;        // 0..7
    const int h0   = (blockIdx.x & 31) * HT; // h-tile origin
    const size_t seq_base = (size_t)b * S_LEN * H_DIM;

    if (wid == 2) {
        // ---------------- loader wave ----------------
        // op k of tile t: rows t*TS+2k .. +2k+1; lane covers row lane>>5,
        // 512B contiguous: col (lane&31)*4. LDS dest wave-uniform base
        // + lane*16 -> linear [s_local][h_local].
        const float* gsrc0 = x + seq_base + (size_t)(lane >> 5) * H_DIM
                               + h0 + (lane & 31) * 4;

        asm volatile("s_waitcnt vmcnt(0) lgkmcnt(0)" ::: "memory");

        auto issue_tile = [&](int t, int buf) {
            const float* g = gsrc0 + (size_t)t * TS * H_DIM;
#pragma unroll
            for (int k = 0; k < OPS; ++k) {
                __builtin_amdgcn_global_load_lds(
                    (gbl_u32*)(g + (size_t)k * 2 * H_DIM),
                    (lds_u32*)&xbuf[buf][k * 2][0],
                    16, 0, 0);
            }
        };

        issue_tile(0, 0);
        issue_tile(1, 1);

        for (int t = 0; t < NT; ++t) {
            // Counter holds only loads: newer-than-L(t) = L(t+1) (16 ops).
            if (t == NT - 1) asm volatile("s_waitcnt vmcnt(0)"  ::: "memory");
            else             asm volatile("s_waitcnt vmcnt(16)" ::: "memory");
            asm volatile("s_barrier" ::: "memory");              // #t
            // xbuf[(t+2)%3] == xbuf[(t-1)%3]: consumed before barrier #t.
            if (t + 2 < NT) issue_tile(t + 2, (t + 2) % 3);
        }
        asm volatile("s_barrier" ::: "memory");                  // #NT
    } else if (wid == 3) {
        // ---------------- storer wave ----------------
        float* gdst0 = out + seq_base + (size_t)(lane >> 5) * H_DIM
                           + h0 + (lane & 31) * 4;

        // OPS x 1KB nontemporal dwordx4 stores (2 rows x 512B each).
        auto flush_tile = [&](int t) {
            float*       gd   = gdst0 + (size_t)t * TS * H_DIM;
            const float* lsrc = &obuf[t & 1][0][0];
#pragma unroll
            for (int k = 0; k < OPS; ++k) {
                const f32x4 v = *(const f32x4*)(lsrc + k * 256 + lane * 4);
                __builtin_nontemporal_store(v, (f32x4*)(gd + (size_t)k * 2 * H_DIM));
            }
        };

        for (int t = 0; t < NT; ++t) {
            asm volatile("s_barrier" ::: "memory");              // #t
            if (t >= 1) {
                flush_tile(t - 1);
                // obuf[(t-1)&1] ds_reads must retire before compute rewrites
                // that parity during iter t+1 (after barrier #t+1).
                asm volatile("s_waitcnt lgkmcnt(0)" ::: "memory");
            }
        }
        asm volatile("s_barrier" ::: "memory");                  // #NT
        flush_tile(NT - 1);
    } else {
        // ---------------- compute waves (wid 0,1) ----------------
        const float thr   = thr_p[0];
        const float decay = decay_p[0];
        const int   hoff  = wid * 64 + lane;   // column within the 128-wide tile

        float dmem = 0.0f;   // carries decay*mem (exactly one rounding)
        float ref  = 0.0f;

        for (int t = 0; t < NT; ++t) {
            asm volatile("s_barrier" ::: "memory");              // #t
            const float* xb = &xbuf[t % 3][0][0];
            float*       ob = &obuf[t & 1][0][0];
#pragma unroll
            for (int s = 0; s < TS; ++s) {
                const float xv   = xb[s * HT + hoff];
                const float memn = __fadd_rn(dmem, xv);          // decay*mem + x
                const float refm = fmaxf(__fadd_rn(ref, -1.0f), 0.0f);
                const bool  spk  = (refm == 0.0f) & (memn > thr);
                const float dm   = __fmul_rn(decay, memn);       // speculative decay
                dmem = spk ? 0.0f : dm;                          // exact (decay*0 = 0)
                ref  = __fadd_rn(refm, spk ? 5.0f : 0.0f);       // exact
                ob[s * HT + hoff] = spk ? 1.0f : 0.0f;
            }
            // xbuf reads + obuf writes retired before next barrier.
            asm volatile("s_waitcnt lgkmcnt(0)" ::: "memory");
        }
        asm volatile("s_barrier" ::: "memory");                  // #NT
    }
}

extern "C" void kernel_launch(void* const* d_in, const int* in_sizes, int n_in,
                              void* d_out, int out_size, void* d_ws, size_t ws_size,
                              hipStream_t stream) {
    const float* x     = (const float*)d_in[0];
    const float* thr   = (const float*)d_in[1];
    const float* decay = (const float*)d_in[2];
    float*       out   = (float*)d_out;

    // 256 blocks x 256 threads (2 compute + loader + storer per 128-wide
    // h-tile); 1 block/CU.
    lif_kernel<<<dim3(256), dim3(256), 0, stream>>>(x, thr, decay, out);
}